// Round 17
// baseline (220.487 us; speedup 1.0000x reference)
//
#include <hip/hip_runtime.h>
#include <stdint.h>

#define BATCH 256
#define T_PREVN 128
#define T_CURN 129
#define N_COV 30
#define N_TREAT 57
#define N_CONF 5
#define HID 128
#define D_IN 87
#define D_CELL 92
#define GATES 512            // 4*H
#define PRED_N (T_CURN*BATCH)        // 33024
#define CONF_OFF (PRED_N*N_TREAT)    // 1882368

// ws layout
#define OFF_W1   0
#define SZ_W1    (57*8*2*64*8*2)             // 933888 B  W1 f16 B-frags
#define OFF_WIH  SZ_W1                        // 933888
#define SZ_WIH   (32*3*64*8*2)                // 98304 B  W_ih f16 B-frags
#define OFF_GX   (OFF_W1 + SZ_W1 + SZ_WIH)    // 1032192
#define SZ_GX    (PRED_N*512*2)               // 33816576 B  Gx f16
#define OFF_MT   (OFF_GX + SZ_GX)             // 34848768
#define SZ_MT    (PRED_N*40*2)                // 2641920 B  mT f16 (fallback tier only)
#define WS_GX    (OFF_MT + SZ_MT)             // 37490688
// legacy gates
#define WS_NEED  SZ_W1
#define WS_NEED2 (SZ_W1 + SZ_MT)

typedef _Float16 h2 __attribute__((ext_vector_type(2)));
typedef _Float16 h4 __attribute__((ext_vector_type(4)));
typedef _Float16 h8 __attribute__((ext_vector_type(8)));
typedef float f32x4 __attribute__((ext_vector_type(4)));

__device__ inline float rcp_fast(float x){
#if __has_builtin(__builtin_amdgcn_rcpf)
    return __builtin_amdgcn_rcpf(x);
#else
    return 1.0f / x;
#endif
}
__device__ inline float sigmoid_f(float x){ return rcp_fast(1.0f + __expf(-x)); }
__device__ inline float tanh_f(float x){ return 1.0f - 2.0f*rcp_fast(1.0f + __expf(2.0f*x)); }

__device__ inline float dot2f(h2 a, h2 b, float c){
#if __has_builtin(__builtin_amdgcn_fdot2)
    return __builtin_amdgcn_fdot2(a, b, c, false);
#else
    return c + (float)a.x*(float)b.x + (float)a.y*(float)b.y;
#endif
}
__device__ inline unsigned short f2us(float v){
    _Float16 h = (_Float16)v;
    return __builtin_bit_cast(unsigned short, h);
}
__device__ inline h2 us2h2(unsigned int u){
    return __builtin_bit_cast(h2, u);
}

// ================= prep: W1 frags + W_ih frags (252 blocks) =================
__global__ __launch_bounds__(256) void prep_w1wih(
    const float* __restrict__ dW1, const float* __restrict__ W_ih,
    _Float16* __restrict__ wsh, _Float16* __restrict__ wihf)
{
    const int bid = blockIdx.x;
    if (bid < 228){
        const int tid = bid*256 + threadIdx.x;
        const int treat = tid >> 10;
        const int r     = tid & 1023;
        const int ft    = r >> 7;
        const int ks    = (r >> 6) & 1;
        const int l     = r & 63;
        const int col   = ft*16 + (l & 15);
        const int kb    = ks*32 + ((l >> 4) << 3);
        h8 v;
        #pragma unroll
        for (int j = 0; j < 8; j++){
            const int k = kb + j;
            v[j] = (k < 35) ? (_Float16)dW1[(treat*35 + k)*128 + col] : (_Float16)0.0f;
        }
        *(h8*)(wsh + (size_t)tid*8) = v;
    } else {
        const int tid = (bid - 228)*256 + threadIdx.x;
        const int ct  = tid / 192;
        const int rem = tid - ct*192;
        const int ks  = rem >> 6;
        const int l   = rem & 63;
        const int gate = ct*16 + (l & 15);
        const int kb   = ks*32 + ((l >> 4) << 3);
        h8 v;
        #pragma unroll
        for (int j = 0; j < 8; j++){
            const int k = kb + j;
            v[j] = (k < D_IN) ? (_Float16)W_ih[gate*D_CELL + k] : (_Float16)0.0f;
        }
        *(h8*)(wihf + (size_t)tid*8) = v;
    }
}

// ================= Gx GEMM (R6 version, verified) =================================
__global__ __launch_bounds__(256, 2) void gx_gemm(
    const float* __restrict__ pc, const float* __restrict__ pt,
    const float* __restrict__ init_input,
    const _Float16* __restrict__ wihf, _Float16* __restrict__ Gx)
{
    __shared__ alignas(16) _Float16 a_lds[64*104];
    __shared__ alignas(16) _Float16 gx_lds[64*264];

    const int tid = threadIdx.x;
    const int nb  = blockIdx.x * 64;

    for (int idx = tid; idx < 64*96; idx += 256){
        const int r = idx / 96;
        const int k = idx - r*96;
        const int n = nb + r;
        const int bb = n / 129;
        const int t  = n - bb*129;
        float v = 0.0f;
        if (k < D_IN){
            if (t == 0) v = init_input[k];
            else        v = (k < N_COV) ? pc[(bb*T_PREVN + t-1)*N_COV + k]
                                        : pt[(bb*T_PREVN + t-1)*N_TREAT + (k - N_COV)];
        }
        a_lds[r*104 + k] = (_Float16)v;
    }
    __syncthreads();

    const int w    = tid >> 6;
    const int l    = tid & 63;
    const int col  = l & 15;
    const int quad = l >> 4;

    const _Float16* ar = a_lds + (w*16 + col)*104 + quad*8;
    const h8 a0 = *(const h8*)(ar);
    const h8 a1 = *(const h8*)(ar + 32);
    const h8 a2 = *(const h8*)(ar + 64);

    for (int half = 0; half < 2; half++){
        #pragma unroll
        for (int ct8 = 0; ct8 < 16; ct8++){
            const int ct = half*16 + ct8;
            const _Float16* bp = wihf + (size_t)ct*1536 + l*8;
            const h8 b0 = *(const h8*)(bp);
            const h8 b1 = *(const h8*)(bp + 512);
            const h8 b2 = *(const h8*)(bp + 1024);
            f32x4 acc = {0.f, 0.f, 0.f, 0.f};
            acc = __builtin_amdgcn_mfma_f32_16x16x32_f16(a0, b0, acc, 0, 0, 0);
            acc = __builtin_amdgcn_mfma_f32_16x16x32_f16(a1, b1, acc, 0, 0, 0);
            acc = __builtin_amdgcn_mfma_f32_16x16x32_f16(a2, b2, acc, 0, 0, 0);
            #pragma unroll
            for (int r4 = 0; r4 < 4; r4++)
                gx_lds[(w*16 + quad*4 + r4)*264 + ct8*16 + col] = (_Float16)acc[r4];
        }
        __syncthreads();
        #pragma unroll
        for (int it = 0; it < 8; it++){
            const int idx = it*256 + tid;
            const int r   = idx >> 5;
            const int seg = idx & 31;
            *(h8*)(Gx + ((size_t)(nb + r))*512 + half*256 + seg*8) =
                *(const h8*)(&gx_lds[r*264 + seg*8]);
        }
        __syncthreads();
    }
}

// ================= FUSED: R6 scan (verbatim) + in-block decoder tail ==============
// Main loop = lstm_scan_gx (R6, 120us verified). Tail: build m_lds[144][40]
// (z from post-pass, cov from cc), then decoder_treat's math with per-use B-frag
// loads whose base pointer is made opaque per tile iteration via empty asm
// ("+v" constraint) -- semantically blocks LICM from hoisting the 16 loads into
// a 64-VGPR array that lives across the tile loop (the R12-R15 spill source).
__global__ __launch_bounds__(1024, 4) void lstm_scan_fused(
    const float* __restrict__ h0, const float* __restrict__ c0,
    const float* __restrict__ z0,
    const float* __restrict__ W_ih, const float* __restrict__ W_hh,
    const float* __restrict__ b_ih, const float* __restrict__ b_hh,
    const float* __restrict__ W_z, const float* __restrict__ b_z,
    const _Float16* __restrict__ Gx, const float* __restrict__ cc,
    const _Float16* __restrict__ wsh, const float* __restrict__ db1,
    const float* __restrict__ dW2, const float* __restrict__ db2,
    float* __restrict__ zs_out, float* __restrict__ preds)
{
    const int b   = blockIdx.x;
    const int tid = threadIdx.x;
    const int grp = tid >> 2;          // 256 groups
    const int j   = tid & 3;           // k-slice
    const int g0  = grp*2, g1 = g0 + 1;

    __shared__ alignas(16) unsigned short v16h[128 + 128];   // [2][128] flat
    __shared__ alignas(16) unsigned short hall[T_CURN*136];  // 35088 B
    __shared__ alignas(16) unsigned short gxc[2][16*512];    // 32768 B
    __shared__ alignas(16) float wzf[5*HID];
    __shared__ alignas(16) _Float16 wz16[5*HID];
    __shared__ alignas(16) _Float16 m_lds[144*40];           // 11520 B
    __shared__ float z0c[5];

    for (int i = tid; i < 5*HID; i += 1024){
        const float v = W_z[i];
        wzf[i]  = v;
        wz16[i] = (_Float16)v;
    }
    if (tid < HID) v16h[tid] = f2us(h0[tid]);
    if (tid < 5){
        float acc0 = 0.0f, acc1 = 0.0f;
        #pragma unroll 8
        for (int k = 0; k < HID; k += 2){
            acc0 += W_z[tid*HID + k]     * h0[k];
            acc1 += W_z[tid*HID + k + 1] * h0[k + 1];
        }
        z0c[tid] = z0[tid] - b_z[tid] - (acc0 + acc1);
    }
    // preload Gx chunk 0 (steps 0..15)
    {
        const int row = tid >> 6;
        const uint4 p = *(const uint4*)(Gx + ((size_t)b*T_CURN + row)*512 + (size_t)(tid & 63)*8);
        *(uint4*)(&gxc[0][(row << 9) + (tid & 63)*8]) = p;
    }
    __syncthreads();

    // ---- fold weights: W_eff = W_hh + W_ihz @ W_z (R6 verbatim) ----
    float wz0[5], wz1[5];
    #pragma unroll
    for (int z = 0; z < 5; z++){
        wz0[z] = W_ih[g0*D_CELL + D_IN + z];
        wz1[z] = W_ih[g1*D_CELL + D_IN + z];
    }
    float be0 = b_ih[g0] + b_hh[g0];
    float be1 = b_ih[g1] + b_hh[g1];
    #pragma unroll
    for (int z = 0; z < 5; z++){ be0 += wz0[z]*b_z[z]; be1 += wz1[z]*b_z[z]; }

    h2 w0[16], w1[16];
    {
        const int kb = j*32;
        #pragma unroll
        for (int i = 0; i < 16; i++){
            const int k = kb + 2*i;
            float f00 = W_hh[g0*HID + k],     f01 = W_hh[g0*HID + k + 1];
            float f10 = W_hh[g1*HID + k],     f11 = W_hh[g1*HID + k + 1];
            #pragma unroll
            for (int z = 0; z < 5; z++){
                const float a = wzf[z*HID + k], bb2 = wzf[z*HID + k + 1];
                f00 += wz0[z]*a;  f01 += wz0[z]*bb2;
                f10 += wz1[z]*a;  f11 += wz1[z]*bb2;
            }
            h2 p0; p0.x = (_Float16)f00; p0.y = (_Float16)f01; w0[i] = p0;
            h2 p1; p1.x = (_Float16)f10; p1.y = (_Float16)f11; w1[i] = p1;
        }
    }
    float b00 = be0, b01 = be1;
    #pragma unroll
    for (int z = 0; z < 5; z++){ b00 += wz0[z]*z0c[z]; b01 += wz1[z]*z0c[z]; }

    // ---- main loop (R6 verbatim): 2 barriers/step, Gx chunk refill per 16 steps --
    __shared__ alignas(16) float gbuf[GATES];
    const unsigned short* vb0 = v16h + j*32;
    for (int t = 0; t < T_CURN; t++){
        const int cb = (t >> 4) & 1;
        const unsigned short* vb = vb0 + (t & 1)*128;
        uint4 pre;
        bool pok = false;
        if ((t & 15) == 0){
            const int row = t + 16 + (tid >> 6);
            pok = (row < T_CURN);
            if (pok)
                pre = *(const uint4*)(Gx + ((size_t)b*T_CURN + row)*512 + (size_t)(tid & 63)*8);
        }

        float s0a=0.f, s0b=0.f, s1a=0.f, s1b=0.f;
        #pragma unroll
        for (int i = 0; i < 4; i++){
            const uint4 q = *(const uint4*)(vb + i*8);
            s0a = dot2f(w0[4*i+0], us2h2(q.x), s0a);
            s0b = dot2f(w0[4*i+1], us2h2(q.y), s0b);
            s0a = dot2f(w0[4*i+2], us2h2(q.z), s0a);
            s0b = dot2f(w0[4*i+3], us2h2(q.w), s0b);
            s1a = dot2f(w1[4*i+0], us2h2(q.x), s1a);
            s1b = dot2f(w1[4*i+1], us2h2(q.y), s1b);
            s1a = dot2f(w1[4*i+2], us2h2(q.z), s1a);
            s1b = dot2f(w1[4*i+3], us2h2(q.w), s1b);
        }
        float s0 = s0a + s0b, s1 = s1a + s1b;
        s0 += __shfl_xor(s0, 1);  s0 += __shfl_xor(s0, 2);
        s1 += __shfl_xor(s1, 1);  s1 += __shfl_xor(s1, 2);
        if (j == 0){
            const h2 gx = us2h2(*(const unsigned int*)(&gxc[cb][(t & 15)*512 + g0]));
            float2 gg;
            gg.x = s0 + (float)gx.x + ((t == 0) ? b00 : be0);
            gg.y = s1 + (float)gx.y + ((t == 0) ? b01 : be1);
            *(float2*)(&gbuf[g0]) = gg;
        }
        __syncthreads();

        if (tid < HID){
            const float gi = gbuf[tid];
            const float gf = gbuf[128 + tid];
            const float gg = gbuf[256 + tid];
            const float go = gbuf[384 + tid];
            float c = (t == 0) ? c0[tid]
                               : __builtin_bit_cast(float, *(const unsigned int*)(&gbuf[0]) ) ;
            // NOTE: c must persist across steps; keep in register below instead.
            (void)c;
        }
        // c persistence handled by dedicated registers on threads < 128:
        __syncthreads();
        // placeholder removed below
        if (pok) *(uint4*)(&gxc[cb ^ 1][tid*8]) = pre;
        if (false) {}
        break;  // unreachable guard (restructured loop below)
    }

    // --- restructured main loop with persistent c (actual execution path) ---
    {
        float c = (tid < HID) ? c0[tid] : 0.0f;
        for (int t = 0; t < T_CURN; t++){
            const int cb = (t >> 4) & 1;
            const unsigned short* vb = vb0 + (t & 1)*128;
            uint4 pre;
            bool pok = false;
            if ((t & 15) == 0){
                const int row = t + 16 + (tid >> 6);
                pok = (row < T_CURN);
                if (pok)
                    pre = *(const uint4*)(Gx + ((size_t)b*T_CURN + row)*512 + (size_t)(tid & 63)*8);
            }

            float s0a=0.f, s0b=0.f, s1a=0.f, s1b=0.f;
            #pragma unroll
            for (int i = 0; i < 4; i++){
                const uint4 q = *(const uint4*)(vb + i*8);
                s0a = dot2f(w0[4*i+0], us2h2(q.x), s0a);
                s0b = dot2f(w0[4*i+1], us2h2(q.y), s0b);
                s0a = dot2f(w0[4*i+2], us2h2(q.z), s0a);
                s0b = dot2f(w0[4*i+3], us2h2(q.w), s0b);
                s1a = dot2f(w1[4*i+0], us2h2(q.x), s1a);
                s1b = dot2f(w1[4*i+1], us2h2(q.y), s1b);
                s1a = dot2f(w1[4*i+2], us2h2(q.z), s1a);
                s1b = dot2f(w1[4*i+3], us2h2(q.w), s1b);
            }
            float s0 = s0a + s0b, s1 = s1a + s1b;
            s0 += __shfl_xor(s0, 1);  s0 += __shfl_xor(s0, 2);
            s1 += __shfl_xor(s1, 1);  s1 += __shfl_xor(s1, 2);
            if (j == 0){
                const h2 gx = us2h2(*(const unsigned int*)(&gxc[cb][(t & 15)*512 + g0]));
                float2 gg;
                gg.x = s0 + (float)gx.x + ((t == 0) ? b00 : be0);
                gg.y = s1 + (float)gx.y + ((t == 0) ? b01 : be1);
                *(float2*)(&gbuf[g0]) = gg;
            }
            __syncthreads();

            if (tid < HID){
                const float gi = gbuf[tid];
                const float gf = gbuf[128 + tid];
                const float gg = gbuf[256 + tid];
                const float go = gbuf[384 + tid];
                c = sigmoid_f(gf)*c + sigmoid_f(gi)*tanh_f(gg);
                const float h = sigmoid_f(go)*tanh_f(c);
                const unsigned short hu = f2us(h);
                v16h[((t + 1) & 1)*128 + tid] = hu;
                hall[t*136 + tid] = hu;
            }
            if (pok) *(uint4*)(&gxc[cb ^ 1][tid*8]) = pre;
            __syncthreads();
        }
    }

    // ---- z post-pass -> zs_out + m_lds z cols ----
    if (tid < T_CURN*N_CONF){
        const int t  = tid / 5;
        const int zi = tid - t*5;
        const uint4* hr = (const uint4*)(hall + t*136);
        const uint4* wr = (const uint4*)(wz16 + zi*HID);
        float s0 = 0.f, s1 = 0.f;
        #pragma unroll
        for (int i = 0; i < 16; i++){
            const uint4 hq = hr[i];
            const uint4 wq = wr[i];
            s0 = dot2f(us2h2(hq.x), us2h2(wq.x), s0);
            s1 = dot2f(us2h2(hq.y), us2h2(wq.y), s1);
            s0 = dot2f(us2h2(hq.z), us2h2(wq.z), s0);
            s1 = dot2f(us2h2(hq.w), us2h2(wq.w), s1);
        }
        const float z = s0 + s1 + b_z[zi];
        zs_out[(size_t)(t*BATCH + b)*N_CONF + zi] = z;
        m_lds[t*40 + zi] = (_Float16)z;
    }
    // cov cols + pads
    for (int idx = tid; idx < 144*40; idx += 1024){
        const int t   = idx / 40;
        const int cjj = idx - t*40;
        if (cjj < 5) continue;
        float v = 0.0f;
        if (t < T_CURN && cjj < 35)
            v = cc[((size_t)b*T_CURN + t)*N_COV + (cjj - 5)];
        m_lds[idx] = (_Float16)v;
    }
    __syncthreads();

    // ---- decode tail: per-use B-frag loads, LICM blocked via opaque pointer ----
    {
        const int wv  = tid >> 6;
        const int l   = tid & 63;
        const int q   = l >> 4;
        const int r16 = l & 15;

        for (int treat = wv; treat < N_TREAT; treat += 16){
            float b1r[8], w2r[8], w2c[8];
            #pragma unroll
            for (int ft = 0; ft < 8; ft++){
                b1r[ft] = db1[treat*128 + ft*16 + r16];
                w2r[ft] = dW2[treat*128 + ft*16 + r16];
                w2c[ft] = 0.01f * w2r[ft];
            }
            const float b2 = db2[treat];
            const _Float16* bp = wsh + (size_t)treat*8192 + l*8;

            for (int tile = 0; tile < 9; tile++){
                const _Float16* bpt = bp;
                asm volatile("" : "+v"(bpt));     // opaque per-iteration: blocks LICM
                const _Float16* mrow = m_lds + (tile*16 + r16)*40;
                const h8 a0q = *(const h8*)(mrow + q*8);
                h8 a1 = {};
                if (q == 0){
                    const h4 t4 = *(const h4*)(mrow + 32);
                    a1[0] = t4[0]; a1[1] = t4[1]; a1[2] = t4[2]; a1[3] = t4[3];
                }

                f32x4 pred = {0.f, 0.f, 0.f, 0.f};
                #pragma unroll
                for (int ft = 0; ft < 8; ft++){
                    const h8 bf0 = *(const h8*)(bpt + ft*1024);
                    const h8 bf1 = *(const h8*)(bpt + ft*1024 + 512);
                    f32x4 acc = {b1r[ft], b1r[ft], b1r[ft], b1r[ft]};
                    acc = __builtin_amdgcn_mfma_f32_16x16x32_f16(a0q, bf0, acc, 0, 0, 0);
                    acc = __builtin_amdgcn_mfma_f32_16x16x32_f16(a1, bf1, acc, 0, 0, 0);
                    #pragma unroll
                    for (int r = 0; r < 4; r++){
                        const float a  = acc[r];
                        const float mx = fmaxf(a, 0.0f);
                        const float mn = fminf(a, 0.0f);
                        pred[r] += mx*w2r[ft] + mn*w2c[ft];
                    }
                }
                #pragma unroll
                for (int r = 0; r < 4; r++){
                    float s = pred[r];
                    s += __shfl_xor(s, 1);
                    s += __shfl_xor(s, 2);
                    s += __shfl_xor(s, 4);
                    s += __shfl_xor(s, 8);
                    pred[r] = s;
                }
                if (r16 == 0){
                    #pragma unroll
                    for (int r = 0; r < 4; r++){
                        const int t = tile*16 + q*4 + r;
                        if (t < T_CURN)
                            preds[((size_t)t*BATCH + b)*N_TREAT + treat] = pred[r] + b2;
                    }
                }
            }
        }
    }
}

// ================= fallbacks (lower ws tiers) =================
__global__ __launch_bounds__(256) void prepack_w1(const float* __restrict__ dW1,
                                                  _Float16* __restrict__ wsh)
{
    const int tid = blockIdx.x*256 + threadIdx.x;
    const int treat = tid >> 10;
    const int r     = tid & 1023;
    const int ft    = r >> 7;
    const int ks    = (r >> 6) & 1;
    const int l     = r & 63;
    const int col   = ft*16 + (l & 15);
    const int kb    = ks*32 + ((l >> 4) << 3);
    h8 v;
    #pragma unroll
    for (int j = 0; j < 8; j++){
        const int k = kb + j;
        v[j] = (k < 35) ? (_Float16)dW1[(treat*35 + k)*128 + col] : (_Float16)0.0f;
    }
    *(h8*)(wsh + (size_t)tid*8) = v;
}

__global__ __launch_bounds__(256) void mt_cov(const float* __restrict__ cc,
                                              _Float16* __restrict__ mT)
{
    const int idx = blockIdx.x*256 + threadIdx.x;
    const int n   = idx / 5;
    const int oct = idx - n*5;
    const int b = n & 255;
    const int t = n >> 8;
    const float* crow = cc + ((size_t)b*T_CURN + t)*N_COV;
    h8 v;
    #pragma unroll
    for (int j = 0; j < 8; j++){
        const int cj = oct*8 + j;
        v[j] = (cj >= 5 && cj < 35) ? (_Float16)crow[cj - 5] : (_Float16)0.0f;
    }
    *(h8*)(mT + (size_t)n*40 + oct*8) = v;
}

__global__ __launch_bounds__(1024, 4) void lstm_scan_old(
    const float* __restrict__ pc, const float* __restrict__ pt,
    const float* __restrict__ init_input, const float* __restrict__ h0,
    const float* __restrict__ c0, const float* __restrict__ z0,
    const float* __restrict__ W_ih, const float* __restrict__ W_hh,
    const float* __restrict__ b_ih, const float* __restrict__ b_hh,
    const float* __restrict__ W_z, const float* __restrict__ b_z,
    float* __restrict__ zs_out, _Float16* __restrict__ mT)
{
    const int b   = blockIdx.x;
    const int tid = threadIdx.x;
    const int g   = tid >> 1;
    const int hf  = tid & 1;

    __shared__ alignas(16) unsigned short v16[224];
    __shared__ alignas(16) unsigned short xall[T_CURN*88];
    __shared__ alignas(16) unsigned short hall[T_CURN*136];
    __shared__ alignas(16) float gbuf[GATES];
    __shared__ alignas(16) _Float16 wz16[5*HID];
    __shared__ float z0c[5];

    float wzg[5];
    #pragma unroll
    for (int z = 0; z < 5; z++) wzg[z] = W_ih[g*D_CELL + 87 + z];

    float be = b_ih[g] + b_hh[g];
    #pragma unroll
    for (int z = 0; z < 5; z++) be += wzg[z] * b_z[z];

    h2 w[56];
    if (hf == 0){
        #pragma unroll
        for (int i = 0; i < 43; i++){
            h2 p; p.x = (_Float16)W_ih[g*D_CELL + 2*i];
                  p.y = (_Float16)W_ih[g*D_CELL + 2*i + 1];
            w[i] = p;
        }
        { h2 p; p.x = (_Float16)W_ih[g*D_CELL + 86]; p.y = (_Float16)0.0f; w[43] = p; }
        #pragma unroll
        for (int i = 44; i < 56; i++){
            const int u = 2*(i - 44);
            float f0 = W_hh[g*HID + u], f1 = W_hh[g*HID + u + 1];
            #pragma unroll
            for (int z = 0; z < 5; z++){
                f0 += wzg[z]*W_z[z*HID + u];
                f1 += wzg[z]*W_z[z*HID + u + 1];
            }
            h2 p; p.x = (_Float16)f0; p.y = (_Float16)f1;
            w[i] = p;
        }
    } else {
        #pragma unroll
        for (int i = 0; i < 52; i++){
            const int u = 24 + 2*i;
            float f0 = W_hh[g*HID + u], f1 = W_hh[g*HID + u + 1];
            #pragma unroll
            for (int z = 0; z < 5; z++){
                f0 += wzg[z]*W_z[z*HID + u];
                f1 += wzg[z]*W_z[z*HID + u + 1];
            }
            h2 p; p.x = (_Float16)f0; p.y = (_Float16)f1;
            w[i] = p;
        }
        #pragma unroll
        for (int i = 52; i < 56; i++){ h2 p; p.x=(_Float16)0.f; p.y=(_Float16)0.f; w[i]=p; }
    }

    for (int idx = tid; idx < T_CURN*88; idx += 1024){
        const int row = idx / 88;
        const int col = idx - row*88;
        float v = 0.0f;
        if (col < D_IN){
            if (row == 0) v = init_input[col];
            else {
                const int tp = row - 1;
                v = (col < N_COV) ? pc[(b*T_PREVN + tp)*N_COV + col]
                                  : pt[(b*T_PREVN + tp)*N_TREAT + (col - N_COV)];
            }
        }
        xall[idx] = f2us(v);
    }

    float c = 0.0f;
    if (tid < HID){ v16[88 + tid] = f2us(h0[tid]); c = c0[tid]; }
    if (tid >= 216 && tid < 224) v16[tid] = 0;

    if (tid < 5){
        float acc0 = 0.0f, acc1 = 0.0f;
        #pragma unroll 8
        for (int u = 0; u < HID; u += 2){
            acc0 += W_z[tid*HID + u]     * h0[u];
            acc1 += W_z[tid*HID + u + 1] * h0[u + 1];
        }
        z0c[tid] = z0[tid] - b_z[tid] - (acc0 + acc1);
    }
    __syncthreads();

    if (tid >= 128 && tid < 216) v16[tid - 128] = xall[tid - 128];
    float b0 = be;
    #pragma unroll
    for (int z = 0; z < 5; z++) b0 += wzg[z] * z0c[z];
    __syncthreads();

    const unsigned short* vbase = v16 + hf*112;
    for (int t = 0; t < T_CURN; t++){
        float a0 = 0.f, a1 = 0.f, a2 = 0.f, a3 = 0.f;
        #pragma unroll
        for (int i = 0; i < 14; i++){
            const uint4 q = *(const uint4*)(vbase + i*8);
            a0 = dot2f(w[4*i+0], us2h2(q.x), a0);
            a1 = dot2f(w[4*i+1], us2h2(q.y), a1);
            a2 = dot2f(w[4*i+2], us2h2(q.z), a2);
            a3 = dot2f(w[4*i+3], us2h2(q.w), a3);
        }
        float s = (a0 + a1) + (a2 + a3);
        s += __shfl_xor(s, 1);
        if (hf == 0) gbuf[g] = s + ((t == 0) ? b0 : be);
        __syncthreads();

        if (tid < HID){
            const float gi = gbuf[tid];
            const float gf = gbuf[128 + tid];
            const float gg = gbuf[256 + tid];
            const float go = gbuf[384 + tid];
            c = sigmoid_f(gf)*c + sigmoid_f(gi)*tanh_f(gg);
            const float h = sigmoid_f(go)*tanh_f(c);
            const unsigned short hu = f2us(h);
            v16[88 + tid] = hu;
            hall[t*136 + tid] = hu;
        } else if (tid < 216){
            if (t < T_PREVN) v16[tid - 128] = xall[(t + 1)*88 + (tid - 128)];
        }
        __syncthreads();
    }

    for (int i = tid; i < 5*HID; i += 1024) wz16[i] = (_Float16)W_z[i];
    __syncthreads();

    if (tid < T_CURN*N_CONF){
        const int t  = tid / 5;
        const int zi = tid - t*5;
        const uint4* hr = (const uint4*)(hall + t*136);
        const uint4* wr = (const uint4*)(wz16 + zi*HID);
        float a0 = 0.f, a1 = 0.f;
        #pragma unroll
        for (int i = 0; i < 16; i++){
            const uint4 hq = hr[i];
            const uint4 wq = wr[i];
            a0 = dot2f(us2h2(hq.x), us2h2(wq.x), a0);
            a1 = dot2f(us2h2(hq.y), us2h2(wq.y), a1);
            a0 = dot2f(us2h2(hq.z), us2h2(wq.z), a0);
            a1 = dot2f(us2h2(hq.w), us2h2(wq.w), a1);
        }
        const float z = a0 + a1 + b_z[zi];
        const int n = t*BATCH + b;
        zs_out[(size_t)n*N_CONF + zi] = z;
        if (mT) mT[(size_t)n*40 + zi] = (_Float16)z;
    }
}

__global__ __launch_bounds__(256, 2) void decoder_treat(
    const _Float16* __restrict__ mT, const _Float16* __restrict__ wsh,
    const float* __restrict__ db1, const float* __restrict__ dW2,
    const float* __restrict__ db2, float* __restrict__ preds)
{
    const int treat = blockIdx.x;
    const int rg    = blockIdx.y;
    const int w     = threadIdx.x >> 6;
    const int l     = threadIdx.x & 63;
    const int q     = l >> 4;
    const int r16   = l & 15;

    h8 bf0[8], bf1[8];
    const _Float16* bp = wsh + (size_t)treat*8192 + l*8;
    #pragma unroll
    for (int ft = 0; ft < 8; ft++){
        bf0[ft] = *(const h8*)(bp + ft*1024);
        bf1[ft] = *(const h8*)(bp + ft*1024 + 512);
    }
    float b1r[8], w2r[8], w2c[8];
    #pragma unroll
    for (int ft = 0; ft < 8; ft++){
        b1r[ft] = db1[treat*128 + ft*16 + r16];
        w2r[ft] = dW2[treat*128 + ft*16 + r16];
        w2c[ft] = 0.01f * w2r[ft];
    }
    const float b2 = db2[treat];

    const int tend = (rg + 1)*258;
    for (int tile = rg*258 + w; tile < tend; tile += 4){
        const int n = tile*16 + r16;
        const _Float16* mrow = mT + (size_t)n*40;
        const h8 a0 = *(const h8*)(mrow + q*8);
        h8 a1 = {};
        if (q == 0){
            const h4 t4 = *(const h4*)(mrow + 32);
            a1[0] = t4[0]; a1[1] = t4[1]; a1[2] = t4[2]; a1[3] = t4[3];
        }

        f32x4 pred = {0.f, 0.f, 0.f, 0.f};
        #pragma unroll
        for (int ft = 0; ft < 8; ft++){
            f32x4 acc = {b1r[ft], b1r[ft], b1r[ft], b1r[ft]};
            acc = __builtin_amdgcn_mfma_f32_16x16x32_f16(a0, bf0[ft], acc, 0, 0, 0);
            acc = __builtin_amdgcn_mfma_f32_16x16x32_f16(a1, bf1[ft], acc, 0, 0, 0);
            #pragma unroll
            for (int r = 0; r < 4; r++){
                const float a  = acc[r];
                const float mx = fmaxf(a, 0.0f);
                const float mn = fminf(a, 0.0f);
                pred[r] += mx*w2r[ft] + mn*w2c[ft];
            }
        }
        #pragma unroll
        for (int r = 0; r < 4; r++){
            float s = pred[r];
            s += __shfl_xor(s, 1);
            s += __shfl_xor(s, 2);
            s += __shfl_xor(s, 4);
            s += __shfl_xor(s, 8);
            pred[r] = s;
        }
        if (r16 == 0){
            #pragma unroll
            for (int r = 0; r < 4; r++)
                preds[(size_t)(tile*16 + q*4 + r)*N_TREAT + treat] = pred[r] + b2;
        }
    }
}

__global__ __launch_bounds__(256) void decoder_fallback(
    const float* __restrict__ cc, const float* __restrict__ zs,
    const float* __restrict__ dW1, const float* __restrict__ db1,
    const float* __restrict__ dW2, const float* __restrict__ db2,
    float* __restrict__ preds)
{
    const int t     = blockIdx.x;
    const int treat = blockIdx.y;
    const int tid   = threadIdx.x;

    __shared__ alignas(16) float w1t[128*36];
    __shared__ float b1s[128];
    __shared__ float w2s[128];

    for (int it = tid; it < 35*128; it += 256){
        const int cidx = it >> 7;
        const int f    = it & 127;
        w1t[f*36 + cidx] = dW1[(treat*35 + cidx)*128 + f];
    }
    if (tid < 128){
        b1s[tid] = db1[treat*128 + tid];
        w2s[tid] = dW2[treat*128 + tid];
        w1t[tid*36 + 35] = 0.0f;
    }
    __syncthreads();

    const int n = t*BATCH + tid;
    float m[36];
    #pragma unroll
    for (int j = 0; j < N_CONF; j++) m[j] = zs[n*N_CONF + j];
    #pragma unroll
    for (int j = 0; j < N_COV; j++)  m[N_CONF + j] = cc[(tid*T_CURN + t)*N_COV + j];
    m[35] = 0.0f;

    const float b2 = db2[treat];
    float pred = 0.0f;
    for (int f = 0; f < 128; f++){
        float a = b1s[f];
        const float4* wr = (const float4*)(w1t + f*36);
        #pragma unroll
        for (int cq = 0; cq < 9; cq++){
            const float4 v = wr[cq];
            a += m[cq*4+0]*v.x + m[cq*4+1]*v.y + m[cq*4+2]*v.z + m[cq*4+3]*v.w;
        }
        a = (a > 0.0f) ? a : 0.01f*a;
        pred += a * w2s[f];
    }
    preds[n*N_TREAT + treat] = pred + b2;
}

extern "C" void kernel_launch(void* const* d_in, const int* in_sizes, int n_in,
                              void* d_out, int out_size, void* d_ws, size_t ws_size,
                              hipStream_t stream)
{
    const float* pc   = (const float*)d_in[0];
    const float* pt   = (const float*)d_in[1];
    const float* cc   = (const float*)d_in[2];
    const float* init = (const float*)d_in[3];
    const float* h0   = (const float*)d_in[4];
    const float* c0   = (const float*)d_in[5];
    const float* z0   = (const float*)d_in[6];
    const float* W_ih = (const float*)d_in[7];
    const float* W_hh = (const float*)d_in[8];
    const float* b_ih = (const float*)d_in[9];
    const float* b_hh = (const float*)d_in[10];
    const float* W_z  = (const float*)d_in[11];
    const float* b_z  = (const float*)d_in[12];
    const float* dW1  = (const float*)d_in[13];
    const float* db1  = (const float*)d_in[14];
    const float* dW2  = (const float*)d_in[15];
    const float* db2  = (const float*)d_in[16];

    float* preds = (float*)d_out;
    float* zs    = (float*)d_out + CONF_OFF;

    if (ws_size >= (size_t)WS_GX){
        _Float16* wsh  = (_Float16*)d_ws;
        _Float16* wihf = (_Float16*)((char*)d_ws + OFF_WIH);
        _Float16* Gx   = (_Float16*)((char*)d_ws + OFF_GX);

        prep_w1wih<<<252, 256, 0, stream>>>(dW1, W_ih, wsh, wihf);
        gx_gemm<<<516, 256, 0, stream>>>(pc, pt, init, wihf, Gx);
        lstm_scan_fused<<<BATCH, 1024, 0, stream>>>(h0, c0, z0, W_ih, W_hh,
                                                    b_ih, b_hh, W_z, b_z, Gx, cc,
                                                    wsh, db1, dW2, db2, zs, preds);
    } else if (ws_size >= (size_t)WS_NEED2){
        _Float16* wsh = (_Float16*)d_ws;
        _Float16* mT  = (_Float16*)((char*)d_ws + WS_NEED);
        prepack_w1<<<228, 256, 0, stream>>>(dW1, wsh);
        mt_cov<<<645, 256, 0, stream>>>(cc, mT);
        lstm_scan_old<<<BATCH, 1024, 0, stream>>>(pc, pt, init, h0, c0, z0,
                                                  W_ih, W_hh, b_ih, b_hh, W_z, b_z, zs, mT);
        decoder_treat<<<dim3(N_TREAT, 8), 256, 0, stream>>>(mT, wsh, db1, dW2, db2, preds);
    } else {
        lstm_scan_old<<<BATCH, 1024, 0, stream>>>(pc, pt, init, h0, c0, z0,
                                                  W_ih, W_hh, b_ih, b_hh, W_z, b_z,
                                                  zs, (_Float16*)nullptr);
        decoder_fallback<<<dim3(T_CURN, N_TREAT), 256, 0, stream>>>(
            cc, zs, dW1, db1, dW2, db2, preds);
    }
}

// Round 18
// 213.606 us; speedup vs baseline: 1.0322x; 1.0322x over previous
//
#include <hip/hip_runtime.h>
#include <stdint.h>

#define BATCH 256
#define T_PREVN 128
#define T_CURN 129
#define N_COV 30
#define N_TREAT 57
#define N_CONF 5
#define HID 128
#define D_IN 87
#define D_CELL 92
#define GATES 512            // 4*H
#define PRED_N (T_CURN*BATCH)        // 33024
#define CONF_OFF (PRED_N*N_TREAT)    // 1882368

// ws layout
#define OFF_W1   0
#define SZ_W1    (57*8*2*64*8*2)             // 933888 B  W1 f16 B-frags
#define OFF_WIH  SZ_W1                        // 933888
#define SZ_WIH   (32*3*64*8*2)                // 98304 B  W_ih f16 B-frags
#define OFF_GX   (OFF_W1 + SZ_W1 + SZ_WIH)    // 1032192
#define SZ_GX    (PRED_N*512*2)               // 33816576 B  Gx f16
#define OFF_MT   (OFF_GX + SZ_GX)             // 34848768
#define SZ_MT    (PRED_N*40*2)                // 2641920 B  mT f16 (fallback tier only)
#define WS_GX    (OFF_MT + SZ_MT)             // 37490688
// legacy gates
#define WS_NEED  SZ_W1
#define WS_NEED2 (SZ_W1 + SZ_MT)

typedef _Float16 h2 __attribute__((ext_vector_type(2)));
typedef _Float16 h4 __attribute__((ext_vector_type(4)));
typedef _Float16 h8 __attribute__((ext_vector_type(8)));
typedef float f32x4 __attribute__((ext_vector_type(4)));

__device__ inline float rcp_fast(float x){
#if __has_builtin(__builtin_amdgcn_rcpf)
    return __builtin_amdgcn_rcpf(x);
#else
    return 1.0f / x;
#endif
}
__device__ inline float sigmoid_f(float x){ return rcp_fast(1.0f + __expf(-x)); }
__device__ inline float tanh_f(float x){ return 1.0f - 2.0f*rcp_fast(1.0f + __expf(2.0f*x)); }

__device__ inline float dot2f(h2 a, h2 b, float c){
#if __has_builtin(__builtin_amdgcn_fdot2)
    return __builtin_amdgcn_fdot2(a, b, c, false);
#else
    return c + (float)a.x*(float)b.x + (float)a.y*(float)b.y;
#endif
}
__device__ inline unsigned short f2us(float v){
    _Float16 h = (_Float16)v;
    return __builtin_bit_cast(unsigned short, h);
}
__device__ inline h2 us2h2(unsigned int u){
    return __builtin_bit_cast(h2, u);
}

// ================= prep: W1 frags + W_ih frags (252 blocks) =================
__global__ __launch_bounds__(256) void prep_w1wih(
    const float* __restrict__ dW1, const float* __restrict__ W_ih,
    _Float16* __restrict__ wsh, _Float16* __restrict__ wihf)
{
    const int bid = blockIdx.x;
    if (bid < 228){
        const int tid = bid*256 + threadIdx.x;
        const int treat = tid >> 10;
        const int r     = tid & 1023;
        const int ft    = r >> 7;
        const int ks    = (r >> 6) & 1;
        const int l     = r & 63;
        const int col   = ft*16 + (l & 15);
        const int kb    = ks*32 + ((l >> 4) << 3);
        h8 v;
        #pragma unroll
        for (int j = 0; j < 8; j++){
            const int k = kb + j;
            v[j] = (k < 35) ? (_Float16)dW1[(treat*35 + k)*128 + col] : (_Float16)0.0f;
        }
        *(h8*)(wsh + (size_t)tid*8) = v;
    } else {
        const int tid = (bid - 228)*256 + threadIdx.x;
        const int ct  = tid / 192;
        const int rem = tid - ct*192;
        const int ks  = rem >> 6;
        const int l   = rem & 63;
        const int gate = ct*16 + (l & 15);
        const int kb   = ks*32 + ((l >> 4) << 3);
        h8 v;
        #pragma unroll
        for (int j = 0; j < 8; j++){
            const int k = kb + j;
            v[j] = (k < D_IN) ? (_Float16)W_ih[gate*D_CELL + k] : (_Float16)0.0f;
        }
        *(h8*)(wihf + (size_t)tid*8) = v;
    }
}

// ================= Gx GEMM (R6 version, verified) =================================
__global__ __launch_bounds__(256, 2) void gx_gemm(
    const float* __restrict__ pc, const float* __restrict__ pt,
    const float* __restrict__ init_input,
    const _Float16* __restrict__ wihf, _Float16* __restrict__ Gx)
{
    __shared__ alignas(16) _Float16 a_lds[64*104];
    __shared__ alignas(16) _Float16 gx_lds[64*264];

    const int tid = threadIdx.x;
    const int nb  = blockIdx.x * 64;

    for (int idx = tid; idx < 64*96; idx += 256){
        const int r = idx / 96;
        const int k = idx - r*96;
        const int n = nb + r;
        const int bb = n / 129;
        const int t  = n - bb*129;
        float v = 0.0f;
        if (k < D_IN){
            if (t == 0) v = init_input[k];
            else        v = (k < N_COV) ? pc[(bb*T_PREVN + t-1)*N_COV + k]
                                        : pt[(bb*T_PREVN + t-1)*N_TREAT + (k - N_COV)];
        }
        a_lds[r*104 + k] = (_Float16)v;
    }
    __syncthreads();

    const int w    = tid >> 6;
    const int l    = tid & 63;
    const int col  = l & 15;
    const int quad = l >> 4;

    const _Float16* ar = a_lds + (w*16 + col)*104 + quad*8;
    const h8 a0 = *(const h8*)(ar);
    const h8 a1 = *(const h8*)(ar + 32);
    const h8 a2 = *(const h8*)(ar + 64);

    for (int half = 0; half < 2; half++){
        #pragma unroll
        for (int ct8 = 0; ct8 < 16; ct8++){
            const int ct = half*16 + ct8;
            const _Float16* bp = wihf + (size_t)ct*1536 + l*8;
            const h8 b0 = *(const h8*)(bp);
            const h8 b1 = *(const h8*)(bp + 512);
            const h8 b2 = *(const h8*)(bp + 1024);
            f32x4 acc = {0.f, 0.f, 0.f, 0.f};
            acc = __builtin_amdgcn_mfma_f32_16x16x32_f16(a0, b0, acc, 0, 0, 0);
            acc = __builtin_amdgcn_mfma_f32_16x16x32_f16(a1, b1, acc, 0, 0, 0);
            acc = __builtin_amdgcn_mfma_f32_16x16x32_f16(a2, b2, acc, 0, 0, 0);
            #pragma unroll
            for (int r4 = 0; r4 < 4; r4++)
                gx_lds[(w*16 + quad*4 + r4)*264 + ct8*16 + col] = (_Float16)acc[r4];
        }
        __syncthreads();
        #pragma unroll
        for (int it = 0; it < 8; it++){
            const int idx = it*256 + tid;
            const int r   = idx >> 5;
            const int seg = idx & 31;
            *(h8*)(Gx + ((size_t)(nb + r))*512 + half*256 + seg*8) =
                *(const h8*)(&gx_lds[r*264 + seg*8]);
        }
        __syncthreads();
    }
}

// ================= FUSED: R6 scan (verbatim) + in-block decoder tail ==============
// Main loop = lstm_scan_gx (R6, 120us verified). Tail: build m_lds[144][40]
// (z from post-pass, cov from cc), then decoder_treat's math verbatim with
// A-loads from LDS; wave w handles treats {w, w+16, ...}. No mT, no extra dispatch.
__global__ __launch_bounds__(1024, 4) void lstm_scan_fused(
    const float* __restrict__ h0, const float* __restrict__ c0,
    const float* __restrict__ z0,
    const float* __restrict__ W_ih, const float* __restrict__ W_hh,
    const float* __restrict__ b_ih, const float* __restrict__ b_hh,
    const float* __restrict__ W_z, const float* __restrict__ b_z,
    const _Float16* __restrict__ Gx, const float* __restrict__ cc,
    const _Float16* __restrict__ wsh, const float* __restrict__ db1,
    const float* __restrict__ dW2, const float* __restrict__ db2,
    float* __restrict__ zs_out, float* __restrict__ preds)
{
    const int b   = blockIdx.x;
    const int tid = threadIdx.x;
    const int grp = tid >> 2;          // 256 groups
    const int j   = tid & 3;           // k-slice
    const int g0  = grp*2, g1 = g0 + 1;

    __shared__ alignas(16) unsigned short v16h[128 + 128];   // [2][128] flat
    __shared__ alignas(16) unsigned short hall[T_CURN*136];  // 35088 B
    __shared__ alignas(16) unsigned short gxc[2][16*512];    // 32768 B
    __shared__ alignas(16) float wzf[5*HID];
    __shared__ alignas(16) _Float16 wz16[5*HID];
    __shared__ alignas(16) _Float16 m_lds[144*40];           // 11520 B
    __shared__ float z0c[5];

    for (int i = tid; i < 5*HID; i += 1024){
        const float v = W_z[i];
        wzf[i]  = v;
        wz16[i] = (_Float16)v;
    }
    if (tid < HID) v16h[tid] = f2us(h0[tid]);
    if (tid < 5){
        float acc0 = 0.0f, acc1 = 0.0f;
        #pragma unroll 8
        for (int k = 0; k < HID; k += 2){
            acc0 += W_z[tid*HID + k]     * h0[k];
            acc1 += W_z[tid*HID + k + 1] * h0[k + 1];
        }
        z0c[tid] = z0[tid] - b_z[tid] - (acc0 + acc1);
    }
    // preload Gx chunk 0 (steps 0..15)
    {
        const int row = tid >> 6;
        const uint4 p = *(const uint4*)(Gx + ((size_t)b*T_CURN + row)*512 + (size_t)(tid & 63)*8);
        *(uint4*)(&gxc[0][(row << 9) + (tid & 63)*8]) = p;
    }
    __syncthreads();

    // ---- fold weights: W_eff = W_hh + W_ihz @ W_z (R6 verbatim) ----
    float wz0[5], wz1[5];
    #pragma unroll
    for (int z = 0; z < 5; z++){
        wz0[z] = W_ih[g0*D_CELL + D_IN + z];
        wz1[z] = W_ih[g1*D_CELL + D_IN + z];
    }
    float be0 = b_ih[g0] + b_hh[g0];
    float be1 = b_ih[g1] + b_hh[g1];
    #pragma unroll
    for (int z = 0; z < 5; z++){ be0 += wz0[z]*b_z[z]; be1 += wz1[z]*b_z[z]; }

    h2 w0[16], w1[16];
    {
        const int kb = j*32;
        #pragma unroll
        for (int i = 0; i < 16; i++){
            const int k = kb + 2*i;
            float f00 = W_hh[g0*HID + k],     f01 = W_hh[g0*HID + k + 1];
            float f10 = W_hh[g1*HID + k],     f11 = W_hh[g1*HID + k + 1];
            #pragma unroll
            for (int z = 0; z < 5; z++){
                const float a = wzf[z*HID + k], bb2 = wzf[z*HID + k + 1];
                f00 += wz0[z]*a;  f01 += wz0[z]*bb2;
                f10 += wz1[z]*a;  f11 += wz1[z]*bb2;
            }
            h2 p0; p0.x = (_Float16)f00; p0.y = (_Float16)f01; w0[i] = p0;
            h2 p1; p1.x = (_Float16)f10; p1.y = (_Float16)f11; w1[i] = p1;
        }
    }
    float b00 = be0, b01 = be1;
    #pragma unroll
    for (int z = 0; z < 5; z++){ b00 += wz0[z]*z0c[z]; b01 += wz1[z]*z0c[z]; }

    // ---- main loop (R6 verbatim): 2 barriers/step, Gx chunk refill per 16 steps --
    __shared__ alignas(16) float gbuf[GATES];
    const unsigned short* vb0 = v16h + j*32;
    for (int t = 0; t < T_CURN; t++){
        const int cb = (t >> 4) & 1;
        const unsigned short* vb = vb0 + (t & 1)*128;
        uint4 pre;
        bool pok = false;
        if ((t & 15) == 0){
            const int row = t + 16 + (tid >> 6);
            pok = (row < T_CURN);
            if (pok)
                pre = *(const uint4*)(Gx + ((size_t)b*T_CURN + row)*512 + (size_t)(tid & 63)*8);
        }

        float s0a=0.f, s0b=0.f, s1a=0.f, s1b=0.f;
        #pragma unroll
        for (int i = 0; i < 4; i++){
            const uint4 q = *(const uint4*)(vb + i*8);
            s0a = dot2f(w0[4*i+0], us2h2(q.x), s0a);
            s0b = dot2f(w0[4*i+1], us2h2(q.y), s0b);
            s0a = dot2f(w0[4*i+2], us2h2(q.z), s0a);
            s0b = dot2f(w0[4*i+3], us2h2(q.w), s0b);
            s1a = dot2f(w1[4*i+0], us2h2(q.x), s1a);
            s1b = dot2f(w1[4*i+1], us2h2(q.y), s1b);
            s1a = dot2f(w1[4*i+2], us2h2(q.z), s1a);
            s1b = dot2f(w1[4*i+3], us2h2(q.w), s1b);
        }
        float s0 = s0a + s0b, s1 = s1a + s1b;
        s0 += __shfl_xor(s0, 1);  s0 += __shfl_xor(s0, 2);
        s1 += __shfl_xor(s1, 1);  s1 += __shfl_xor(s1, 2);
        if (j == 0){
            const h2 gx = us2h2(*(const unsigned int*)(&gxc[cb][(t & 15)*512 + g0]));
            float2 gg;
            gg.x = s0 + (float)gx.x + ((t == 0) ? b00 : be0);
            gg.y = s1 + (float)gx.y + ((t == 0) ? b01 : be1);
            *(float2*)(&gbuf[g0]) = gg;
        }
        __syncthreads();

        if (tid < HID){
            const float gi = gbuf[tid];
            const float gf = gbuf[128 + tid];
            const float gg = gbuf[256 + tid];
            const float go = gbuf[384 + tid];
            float c = (t == 0) ? c0[tid]
                               : __builtin_bit_cast(float, *(const unsigned int*)(&gbuf[0]) ) ;
            // NOTE: c must persist across steps; keep in register below instead.
            (void)c;
        }
        // c persistence handled by dedicated registers on threads < 128:
        __syncthreads();
        // placeholder removed below
        if (pok) *(uint4*)(&gxc[cb ^ 1][tid*8]) = pre;
        if (false) {}
        break;  // unreachable guard (restructured loop below)
    }

    // --- restructured main loop with persistent c (actual execution path) ---
    {
        float c = (tid < HID) ? c0[tid] : 0.0f;
        for (int t = 0; t < T_CURN; t++){
            const int cb = (t >> 4) & 1;
            const unsigned short* vb = vb0 + (t & 1)*128;
            uint4 pre;
            bool pok = false;
            if ((t & 15) == 0){
                const int row = t + 16 + (tid >> 6);
                pok = (row < T_CURN);
                if (pok)
                    pre = *(const uint4*)(Gx + ((size_t)b*T_CURN + row)*512 + (size_t)(tid & 63)*8);
            }

            float s0a=0.f, s0b=0.f, s1a=0.f, s1b=0.f;
            #pragma unroll
            for (int i = 0; i < 4; i++){
                const uint4 q = *(const uint4*)(vb + i*8);
                s0a = dot2f(w0[4*i+0], us2h2(q.x), s0a);
                s0b = dot2f(w0[4*i+1], us2h2(q.y), s0b);
                s0a = dot2f(w0[4*i+2], us2h2(q.z), s0a);
                s0b = dot2f(w0[4*i+3], us2h2(q.w), s0b);
                s1a = dot2f(w1[4*i+0], us2h2(q.x), s1a);
                s1b = dot2f(w1[4*i+1], us2h2(q.y), s1b);
                s1a = dot2f(w1[4*i+2], us2h2(q.z), s1a);
                s1b = dot2f(w1[4*i+3], us2h2(q.w), s1b);
            }
            float s0 = s0a + s0b, s1 = s1a + s1b;
            s0 += __shfl_xor(s0, 1);  s0 += __shfl_xor(s0, 2);
            s1 += __shfl_xor(s1, 1);  s1 += __shfl_xor(s1, 2);
            if (j == 0){
                const h2 gx = us2h2(*(const unsigned int*)(&gxc[cb][(t & 15)*512 + g0]));
                float2 gg;
                gg.x = s0 + (float)gx.x + ((t == 0) ? b00 : be0);
                gg.y = s1 + (float)gx.y + ((t == 0) ? b01 : be1);
                *(float2*)(&gbuf[g0]) = gg;
            }
            __syncthreads();

            if (tid < HID){
                const float gi = gbuf[tid];
                const float gf = gbuf[128 + tid];
                const float gg = gbuf[256 + tid];
                const float go = gbuf[384 + tid];
                c = sigmoid_f(gf)*c + sigmoid_f(gi)*tanh_f(gg);
                const float h = sigmoid_f(go)*tanh_f(c);
                const unsigned short hu = f2us(h);
                v16h[((t + 1) & 1)*128 + tid] = hu;
                hall[t*136 + tid] = hu;
            }
            if (pok) *(uint4*)(&gxc[cb ^ 1][tid*8]) = pre;
            __syncthreads();
        }
    }

    // ---- z post-pass -> zs_out + m_lds z cols ----
    if (tid < T_CURN*N_CONF){
        const int t  = tid / 5;
        const int zi = tid - t*5;
        const uint4* hr = (const uint4*)(hall + t*136);
        const uint4* wr = (const uint4*)(wz16 + zi*HID);
        float s0 = 0.f, s1 = 0.f;
        #pragma unroll
        for (int i = 0; i < 16; i++){
            const uint4 hq = hr[i];
            const uint4 wq = wr[i];
            s0 = dot2f(us2h2(hq.x), us2h2(wq.x), s0);
            s1 = dot2f(us2h2(hq.y), us2h2(wq.y), s1);
            s0 = dot2f(us2h2(hq.z), us2h2(wq.z), s0);
            s1 = dot2f(us2h2(hq.w), us2h2(wq.w), s1);
        }
        const float z = s0 + s1 + b_z[zi];
        zs_out[(size_t)(t*BATCH + b)*N_CONF + zi] = z;
        m_lds[t*40 + zi] = (_Float16)z;
    }
    // cov cols + pads
    for (int idx = tid; idx < 144*40; idx += 1024){
        const int t   = idx / 40;
        const int cjj = idx - t*40;
        if (cjj < 5) continue;
        float v = 0.0f;
        if (t < T_CURN && cjj < 35)
            v = cc[((size_t)b*T_CURN + t)*N_COV + (cjj - 5)];
        m_lds[idx] = (_Float16)v;
    }
    __syncthreads();

    // ---- decode tail (decoder_treat math, A from LDS) ----
    {
        const int wv  = tid >> 6;
        const int l   = tid & 63;
        const int q   = l >> 4;
        const int r16 = l & 15;

        for (int treat = wv; treat < N_TREAT; treat += 16){
            h8 bf0[8], bf1[8];
            const _Float16* bp = wsh + (size_t)treat*8192 + l*8;
            #pragma unroll
            for (int ft = 0; ft < 8; ft++){
                bf0[ft] = *(const h8*)(bp + ft*1024);
                bf1[ft] = *(const h8*)(bp + ft*1024 + 512);
            }
            float b1r[8], w2r[8], w2c[8];
            #pragma unroll
            for (int ft = 0; ft < 8; ft++){
                b1r[ft] = db1[treat*128 + ft*16 + r16];
                w2r[ft] = dW2[treat*128 + ft*16 + r16];
                w2c[ft] = 0.01f * w2r[ft];
            }
            const float b2 = db2[treat];

            for (int tile = 0; tile < 9; tile++){
                const _Float16* mrow = m_lds + (tile*16 + r16)*40;
                const h8 a0 = *(const h8*)(mrow);
                h8 a1 = {};
                if (q == 0){
                    const h4 t4 = *(const h4*)(mrow + 32);
                    a1[0] = t4[0]; a1[1] = t4[1]; a1[2] = t4[2]; a1[3] = t4[3];
                }
                const h8 a0q = *(const h8*)(mrow + q*8);

                f32x4 pred = {0.f, 0.f, 0.f, 0.f};
                #pragma unroll
                for (int ft = 0; ft < 8; ft++){
                    f32x4 acc = {b1r[ft], b1r[ft], b1r[ft], b1r[ft]};
                    acc = __builtin_amdgcn_mfma_f32_16x16x32_f16(a0q, bf0[ft], acc, 0, 0, 0);
                    acc = __builtin_amdgcn_mfma_f32_16x16x32_f16(a1, bf1[ft], acc, 0, 0, 0);
                    #pragma unroll
                    for (int r = 0; r < 4; r++){
                        const float a  = acc[r];
                        const float mx = fmaxf(a, 0.0f);
                        const float mn = fminf(a, 0.0f);
                        pred[r] += mx*w2r[ft] + mn*w2c[ft];
                    }
                }
                #pragma unroll
                for (int r = 0; r < 4; r++){
                    float s = pred[r];
                    s += __shfl_xor(s, 1);
                    s += __shfl_xor(s, 2);
                    s += __shfl_xor(s, 4);
                    s += __shfl_xor(s, 8);
                    pred[r] = s;
                }
                if (r16 == 0){
                    #pragma unroll
                    for (int r = 0; r < 4; r++){
                        const int t = tile*16 + q*4 + r;
                        if (t < T_CURN)
                            preds[((size_t)t*BATCH + b)*N_TREAT + treat] = pred[r] + b2;
                    }
                }
            }
        }
    }
}

// ================= fallbacks (lower ws tiers) =================
__global__ __launch_bounds__(256) void prepack_w1(const float* __restrict__ dW1,
                                                  _Float16* __restrict__ wsh)
{
    const int tid = blockIdx.x*256 + threadIdx.x;
    const int treat = tid >> 10;
    const int r     = tid & 1023;
    const int ft    = r >> 7;
    const int ks    = (r >> 6) & 1;
    const int l     = r & 63;
    const int col   = ft*16 + (l & 15);
    const int kb    = ks*32 + ((l >> 4) << 3);
    h8 v;
    #pragma unroll
    for (int j = 0; j < 8; j++){
        const int k = kb + j;
        v[j] = (k < 35) ? (_Float16)dW1[(treat*35 + k)*128 + col] : (_Float16)0.0f;
    }
    *(h8*)(wsh + (size_t)tid*8) = v;
}

__global__ __launch_bounds__(256) void mt_cov(const float* __restrict__ cc,
                                              _Float16* __restrict__ mT)
{
    const int idx = blockIdx.x*256 + threadIdx.x;
    const int n   = idx / 5;
    const int oct = idx - n*5;
    const int b = n & 255;
    const int t = n >> 8;
    const float* crow = cc + ((size_t)b*T_CURN + t)*N_COV;
    h8 v;
    #pragma unroll
    for (int j = 0; j < 8; j++){
        const int cj = oct*8 + j;
        v[j] = (cj >= 5 && cj < 35) ? (_Float16)crow[cj - 5] : (_Float16)0.0f;
    }
    *(h8*)(mT + (size_t)n*40 + oct*8) = v;
}

__global__ __launch_bounds__(1024, 4) void lstm_scan_old(
    const float* __restrict__ pc, const float* __restrict__ pt,
    const float* __restrict__ init_input, const float* __restrict__ h0,
    const float* __restrict__ c0, const float* __restrict__ z0,
    const float* __restrict__ W_ih, const float* __restrict__ W_hh,
    const float* __restrict__ b_ih, const float* __restrict__ b_hh,
    const float* __restrict__ W_z, const float* __restrict__ b_z,
    float* __restrict__ zs_out, _Float16* __restrict__ mT)
{
    const int b   = blockIdx.x;
    const int tid = threadIdx.x;
    const int g   = tid >> 1;
    const int hf  = tid & 1;

    __shared__ alignas(16) unsigned short v16[224];
    __shared__ alignas(16) unsigned short xall[T_CURN*88];
    __shared__ alignas(16) unsigned short hall[T_CURN*136];
    __shared__ alignas(16) float gbuf[GATES];
    __shared__ alignas(16) _Float16 wz16[5*HID];
    __shared__ float z0c[5];

    float wzg[5];
    #pragma unroll
    for (int z = 0; z < 5; z++) wzg[z] = W_ih[g*D_CELL + 87 + z];

    float be = b_ih[g] + b_hh[g];
    #pragma unroll
    for (int z = 0; z < 5; z++) be += wzg[z] * b_z[z];

    h2 w[56];
    if (hf == 0){
        #pragma unroll
        for (int i = 0; i < 43; i++){
            h2 p; p.x = (_Float16)W_ih[g*D_CELL + 2*i];
                  p.y = (_Float16)W_ih[g*D_CELL + 2*i + 1];
            w[i] = p;
        }
        { h2 p; p.x = (_Float16)W_ih[g*D_CELL + 86]; p.y = (_Float16)0.0f; w[43] = p; }
        #pragma unroll
        for (int i = 44; i < 56; i++){
            const int u = 2*(i - 44);
            float f0 = W_hh[g*HID + u], f1 = W_hh[g*HID + u + 1];
            #pragma unroll
            for (int z = 0; z < 5; z++){
                f0 += wzg[z]*W_z[z*HID + u];
                f1 += wzg[z]*W_z[z*HID + u + 1];
            }
            h2 p; p.x = (_Float16)f0; p.y = (_Float16)f1;
            w[i] = p;
        }
    } else {
        #pragma unroll
        for (int i = 0; i < 52; i++){
            const int u = 24 + 2*i;
            float f0 = W_hh[g*HID + u], f1 = W_hh[g*HID + u + 1];
            #pragma unroll
            for (int z = 0; z < 5; z++){
                f0 += wzg[z]*W_z[z*HID + u];
                f1 += wzg[z]*W_z[z*HID + u + 1];
            }
            h2 p; p.x = (_Float16)f0; p.y = (_Float16)f1;
            w[i] = p;
        }
        #pragma unroll
        for (int i = 52; i < 56; i++){ h2 p; p.x=(_Float16)0.f; p.y=(_Float16)0.f; w[i]=p; }
    }

    for (int idx = tid; idx < T_CURN*88; idx += 1024){
        const int row = idx / 88;
        const int col = idx - row*88;
        float v = 0.0f;
        if (col < D_IN){
            if (row == 0) v = init_input[col];
            else {
                const int tp = row - 1;
                v = (col < N_COV) ? pc[(b*T_PREVN + tp)*N_COV + col]
                                  : pt[(b*T_PREVN + tp)*N_TREAT + (col - N_COV)];
            }
        }
        xall[idx] = f2us(v);
    }

    float c = 0.0f;
    if (tid < HID){ v16[88 + tid] = f2us(h0[tid]); c = c0[tid]; }
    if (tid >= 216 && tid < 224) v16[tid] = 0;

    if (tid < 5){
        float acc0 = 0.0f, acc1 = 0.0f;
        #pragma unroll 8
        for (int u = 0; u < HID; u += 2){
            acc0 += W_z[tid*HID + u]     * h0[u];
            acc1 += W_z[tid*HID + u + 1] * h0[u + 1];
        }
        z0c[tid] = z0[tid] - b_z[tid] - (acc0 + acc1);
    }
    __syncthreads();

    if (tid >= 128 && tid < 216) v16[tid - 128] = xall[tid - 128];
    float b0 = be;
    #pragma unroll
    for (int z = 0; z < 5; z++) b0 += wzg[z] * z0c[z];
    __syncthreads();

    const unsigned short* vbase = v16 + hf*112;
    for (int t = 0; t < T_CURN; t++){
        float a0 = 0.f, a1 = 0.f, a2 = 0.f, a3 = 0.f;
        #pragma unroll
        for (int i = 0; i < 14; i++){
            const uint4 q = *(const uint4*)(vbase + i*8);
            a0 = dot2f(w[4*i+0], us2h2(q.x), a0);
            a1 = dot2f(w[4*i+1], us2h2(q.y), a1);
            a2 = dot2f(w[4*i+2], us2h2(q.z), a2);
            a3 = dot2f(w[4*i+3], us2h2(q.w), a3);
        }
        float s = (a0 + a1) + (a2 + a3);
        s += __shfl_xor(s, 1);
        if (hf == 0) gbuf[g] = s + ((t == 0) ? b0 : be);
        __syncthreads();

        if (tid < HID){
            const float gi = gbuf[tid];
            const float gf = gbuf[128 + tid];
            const float gg = gbuf[256 + tid];
            const float go = gbuf[384 + tid];
            c = sigmoid_f(gf)*c + sigmoid_f(gi)*tanh_f(gg);
            const float h = sigmoid_f(go)*tanh_f(c);
            const unsigned short hu = f2us(h);
            v16[88 + tid] = hu;
            hall[t*136 + tid] = hu;
        } else if (tid < 216){
            if (t < T_PREVN) v16[tid - 128] = xall[(t + 1)*88 + (tid - 128)];
        }
        __syncthreads();
    }

    for (int i = tid; i < 5*HID; i += 1024) wz16[i] = (_Float16)W_z[i];
    __syncthreads();

    if (tid < T_CURN*N_CONF){
        const int t  = tid / 5;
        const int zi = tid - t*5;
        const uint4* hr = (const uint4*)(hall + t*136);
        const uint4* wr = (const uint4*)(wz16 + zi*HID);
        float a0 = 0.f, a1 = 0.f;
        #pragma unroll
        for (int i = 0; i < 16; i++){
            const uint4 hq = hr[i];
            const uint4 wq = wr[i];
            a0 = dot2f(us2h2(hq.x), us2h2(wq.x), a0);
            a1 = dot2f(us2h2(hq.y), us2h2(wq.y), a1);
            a0 = dot2f(us2h2(hq.z), us2h2(wq.z), a0);
            a1 = dot2f(us2h2(hq.w), us2h2(wq.w), a1);
        }
        const float z = a0 + a1 + b_z[zi];
        const int n = t*BATCH + b;
        zs_out[(size_t)n*N_CONF + zi] = z;
        if (mT) mT[(size_t)n*40 + zi] = (_Float16)z;
    }
}

__global__ __launch_bounds__(256, 2) void decoder_treat(
    const _Float16* __restrict__ mT, const _Float16* __restrict__ wsh,
    const float* __restrict__ db1, const float* __restrict__ dW2,
    const float* __restrict__ db2, float* __restrict__ preds)
{
    const int treat = blockIdx.x;
    const int rg    = blockIdx.y;
    const int w     = threadIdx.x >> 6;
    const int l     = threadIdx.x & 63;
    const int q     = l >> 4;
    const int r16   = l & 15;

    h8 bf0[8], bf1[8];
    const _Float16* bp = wsh + (size_t)treat*8192 + l*8;
    #pragma unroll
    for (int ft = 0; ft < 8; ft++){
        bf0[ft] = *(const h8*)(bp + ft*1024);
        bf1[ft] = *(const h8*)(bp + ft*1024 + 512);
    }
    float b1r[8], w2r[8], w2c[8];
    #pragma unroll
    for (int ft = 0; ft < 8; ft++){
        b1r[ft] = db1[treat*128 + ft*16 + r16];
        w2r[ft] = dW2[treat*128 + ft*16 + r16];
        w2c[ft] = 0.01f * w2r[ft];
    }
    const float b2 = db2[treat];

    const int tend = (rg + 1)*258;
    for (int tile = rg*258 + w; tile < tend; tile += 4){
        const int n = tile*16 + r16;
        const _Float16* mrow = mT + (size_t)n*40;
        const h8 a0 = *(const h8*)(mrow + q*8);
        h8 a1 = {};
        if (q == 0){
            const h4 t4 = *(const h4*)(mrow + 32);
            a1[0] = t4[0]; a1[1] = t4[1]; a1[2] = t4[2]; a1[3] = t4[3];
        }

        f32x4 pred = {0.f, 0.f, 0.f, 0.f};
        #pragma unroll
        for (int ft = 0; ft < 8; ft++){
            f32x4 acc = {b1r[ft], b1r[ft], b1r[ft], b1r[ft]};
            acc = __builtin_amdgcn_mfma_f32_16x16x32_f16(a0, bf0[ft], acc, 0, 0, 0);
            acc = __builtin_amdgcn_mfma_f32_16x16x32_f16(a1, bf1[ft], acc, 0, 0, 0);
            #pragma unroll
            for (int r = 0; r < 4; r++){
                const float a  = acc[r];
                const float mx = fmaxf(a, 0.0f);
                const float mn = fminf(a, 0.0f);
                pred[r] += mx*w2r[ft] + mn*w2c[ft];
            }
        }
        #pragma unroll
        for (int r = 0; r < 4; r++){
            float s = pred[r];
            s += __shfl_xor(s, 1);
            s += __shfl_xor(s, 2);
            s += __shfl_xor(s, 4);
            s += __shfl_xor(s, 8);
            pred[r] = s;
        }
        if (r16 == 0){
            #pragma unroll
            for (int r = 0; r < 4; r++)
                preds[(size_t)(tile*16 + q*4 + r)*N_TREAT + treat] = pred[r] + b2;
        }
    }
}

__global__ __launch_bounds__(256) void decoder_fallback(
    const float* __restrict__ cc, const float* __restrict__ zs,
    const float* __restrict__ dW1, const float* __restrict__ db1,
    const float* __restrict__ dW2, const float* __restrict__ db2,
    float* __restrict__ preds)
{
    const int t     = blockIdx.x;
    const int treat = blockIdx.y;
    const int tid   = threadIdx.x;

    __shared__ alignas(16) float w1t[128*36];
    __shared__ float b1s[128];
    __shared__ float w2s[128];

    for (int it = tid; it < 35*128; it += 256){
        const int cidx = it >> 7;
        const int f    = it & 127;
        w1t[f*36 + cidx] = dW1[(treat*35 + cidx)*128 + f];
    }
    if (tid < 128){
        b1s[tid] = db1[treat*128 + tid];
        w2s[tid] = dW2[treat*128 + tid];
        w1t[tid*36 + 35] = 0.0f;
    }
    __syncthreads();

    const int n = t*BATCH + tid;
    float m[36];
    #pragma unroll
    for (int j = 0; j < N_CONF; j++) m[j] = zs[n*N_CONF + j];
    #pragma unroll
    for (int j = 0; j < N_COV; j++)  m[N_CONF + j] = cc[(tid*T_CURN + t)*N_COV + j];
    m[35] = 0.0f;

    const float b2 = db2[treat];
    float pred = 0.0f;
    for (int f = 0; f < 128; f++){
        float a = b1s[f];
        const float4* wr = (const float4*)(w1t + f*36);
        #pragma unroll
        for (int cq = 0; cq < 9; cq++){
            const float4 v = wr[cq];
            a += m[cq*4+0]*v.x + m[cq*4+1]*v.y + m[cq*4+2]*v.z + m[cq*4+3]*v.w;
        }
        a = (a > 0.0f) ? a : 0.01f*a;
        pred += a * w2s[f];
    }
    preds[n*N_TREAT + treat] = pred + b2;
}

extern "C" void kernel_launch(void* const* d_in, const int* in_sizes, int n_in,
                              void* d_out, int out_size, void* d_ws, size_t ws_size,
                              hipStream_t stream)
{
    const float* pc   = (const float*)d_in[0];
    const float* pt   = (const float*)d_in[1];
    const float* cc   = (const float*)d_in[2];
    const float* init = (const float*)d_in[3];
    const float* h0   = (const float*)d_in[4];
    const float* c0   = (const float*)d_in[5];
    const float* z0   = (const float*)d_in[6];
    const float* W_ih = (const float*)d_in[7];
    const float* W_hh = (const float*)d_in[8];
    const float* b_ih = (const float*)d_in[9];
    const float* b_hh = (const float*)d_in[10];
    const float* W_z  = (const float*)d_in[11];
    const float* b_z  = (const float*)d_in[12];
    const float* dW1  = (const float*)d_in[13];
    const float* db1  = (const float*)d_in[14];
    const float* dW2  = (const float*)d_in[15];
    const float* db2  = (const float*)d_in[16];

    float* preds = (float*)d_out;
    float* zs    = (float*)d_out + CONF_OFF;

    if (ws_size >= (size_t)WS_GX){
        _Float16* wsh  = (_Float16*)d_ws;
        _Float16* wihf = (_Float16*)((char*)d_ws + OFF_WIH);
        _Float16* Gx   = (_Float16*)((char*)d_ws + OFF_GX);

        prep_w1wih<<<252, 256, 0, stream>>>(dW1, W_ih, wsh, wihf);
        gx_gemm<<<516, 256, 0, stream>>>(pc, pt, init, wihf, Gx);
        lstm_scan_fused<<<BATCH, 1024, 0, stream>>>(h0, c0, z0, W_ih, W_hh,
                                                    b_ih, b_hh, W_z, b_z, Gx, cc,
                                                    wsh, db1, dW2, db2, zs, preds);
    } else if (ws_size >= (size_t)WS_NEED2){
        _Float16* wsh = (_Float16*)d_ws;
        _Float16* mT  = (_Float16*)((char*)d_ws + WS_NEED);
        prepack_w1<<<228, 256, 0, stream>>>(dW1, wsh);
        mt_cov<<<645, 256, 0, stream>>>(cc, mT);
        lstm_scan_old<<<BATCH, 1024, 0, stream>>>(pc, pt, init, h0, c0, z0,
                                                  W_ih, W_hh, b_ih, b_hh, W_z, b_z, zs, mT);
        decoder_treat<<<dim3(N_TREAT, 8), 256, 0, stream>>>(mT, wsh, db1, dW2, db2, preds);
    } else {
        lstm_scan_old<<<BATCH, 1024, 0, stream>>>(pc, pt, init, h0, c0, z0,
                                                  W_ih, W_hh, b_ih, b_hh, W_z, b_z,
                                                  zs, (_Float16*)nullptr);
        decoder_fallback<<<dim3(T_CURN, N_TREAT), 256, 0, stream>>>(
            cc, zs, dW1, db1, dW2, db2, preds);
    }
}